// Round 2
// baseline (423.364 us; speedup 1.0000x reference)
//
#include <hip/hip_runtime.h>
#include <math.h>

#define B 16
#define E 64
#define H 8
#define L 2048
#define M 64
#define PLANE (B*H*E*M)   // 524288 float2 per spectral plane

// exact 32-pt DFT twiddles: CS32[j]=cos(pi j/16), SN32[j]=sin(pi j/16)
constexpr float CS32[32] = {
     1.0f,                    0.9807852804032304f,   0.9238795325112868f,   0.8314696123025452f,
     0.7071067811865476f,     0.5555702330196022f,   0.3826834323650898f,   0.1950903220161283f,
     0.0f,                   -0.1950903220161283f,  -0.3826834323650898f,  -0.5555702330196022f,
    -0.7071067811865476f,    -0.8314696123025452f,  -0.9238795325112868f,  -0.9807852804032304f,
    -1.0f,                   -0.9807852804032304f,  -0.9238795325112868f,  -0.8314696123025452f,
    -0.7071067811865476f,    -0.5555702330196022f,  -0.3826834323650898f,  -0.1950903220161283f,
     0.0f,                    0.1950903220161283f,   0.3826834323650898f,   0.5555702330196022f,
     0.7071067811865476f,     0.8314696123025452f,   0.9238795325112868f,   0.9807852804032304f
};
constexpr float SN32[32] = {
     0.0f,                    0.1950903220161283f,   0.3826834323650898f,   0.5555702330196022f,
     0.7071067811865476f,     0.8314696123025452f,   0.9238795325112868f,   0.9807852804032304f,
     1.0f,                    0.9807852804032304f,   0.9238795325112868f,   0.8314696123025452f,
     0.7071067811865476f,     0.5555702330196022f,   0.3826834323650898f,   0.1950903220161283f,
     0.0f,                   -0.1950903220161283f,  -0.3826834323650898f,  -0.5555702330196022f,
    -0.7071067811865476f,    -0.8314696123025452f,  -0.9238795325112868f,  -0.9807852804032304f,
    -1.0f,                   -0.9807852804032304f,  -0.9238795325112868f,  -0.8314696123025452f,
    -0.7071067811865476f,    -0.5555702330196022f,  -0.3826834323650898f,  -0.1950903220161283f
};

// ---------------------------------------------------------------------------
// Stable complex tanh. tanh(x+iy) = (beta*rho*s + i*t)/(1 + beta*s^2)
// ---------------------------------------------------------------------------
__device__ inline void ctanhf_stable(float x, float y, float& re, float& im) {
    float ax = fabsf(x);
    if (ax > 11.0f) { re = copysignf(1.0f, x); im = 0.0f; return; }
    float t    = tanf(y);
    float beta = 1.0f + t * t;
    float s    = sinhf(x);
    float rho  = sqrtf(1.0f + s * s);
    float den  = 1.0f + beta * s * s;
    re = (beta * rho * s) / den;
    im = t / den;
}

// ---------------------------------------------------------------------------
// Forward DFT, rows of q,k ([B,E,H,L]) -> 64 lowest modes.
// Factorization: l = lane + 64*i.
//   X[m] = sum_lane e^{-i pi m lane/1024} * Y_lane[m mod 32],
//   Y[f] = 32-pt DFT of xs[] (exact table twiddles; real input => f<=16 + conj)
// ---------------------------------------------------------------------------
__global__ __launch_bounds__(256) void k_dft(const float* __restrict__ q,
                                             const float* __restrict__ k,
                                             float2* __restrict__ Xq,
                                             float2* __restrict__ Xk)
{
    int wid  = blockIdx.x * 4 + (threadIdx.x >> 6);   // 0..16383
    int lane = threadIdx.x & 63;
    int tensor = wid >> 13;                           // 0 = q, 1 = k
    int r = wid & 8191;
    int b = r >> 9;
    int h = (r >> 6) & 7;
    int e = r & 63;

    const float* src = (tensor ? k : q) + (((size_t)(b * E + e) * H + h) * L) + lane;
    float xs[32];
    #pragma unroll
    for (int i = 0; i < 32; ++i) xs[i] = src[i * 64];

    // 32-pt DFT over i with exact twiddles
    float Yre[17], Yim[17];
    #pragma unroll
    for (int f = 0; f <= 16; ++f) {
        float ar = 0.f, ai = 0.f;
        #pragma unroll
        for (int i = 0; i < 32; ++i) {
            ar = fmaf(xs[i], CS32[(f * i) & 31], ar);
            ai = fmaf(xs[i], SN32[(f * i) & 31], ai);
        }
        Yre[f] = ar;
        Yim[f] = -ai;
    }

    // u = e^{-i pi lane/1024} (exact, small arg); w = u^m by recurrence
    float us, uc;
    sincosf(-3.0679615757712823e-3f * (float)lane, &us, &uc);
    float wr = 1.f, wi = 0.f;
    float outre = 0.f, outim = 0.f;

    #pragma unroll
    for (int m = 0; m < 64; ++m) {
        int f = m & 31;
        float yr, yi;
        if (f <= 16) { yr = Yre[f];      yi =  Yim[f]; }
        else         { yr = Yre[32 - f]; yi = -Yim[32 - f]; }
        float tr = wr * yr - wi * yi;
        float ti = wr * yi + wi * yr;
        #pragma unroll
        for (int d = 1; d < 64; d <<= 1) {
            tr += __shfl_xor(tr, d);
            ti += __shfl_xor(ti, d);
        }
        if (lane == m) { outre = tr; outim = ti; }
        float t0 = wr * uc - wi * us;   // w *= u
        wi = wr * us + wi * uc;
        wr = t0;
    }

    float2* dst = (tensor ? Xk : Xq) + ((size_t)(b * H + h) * E + e) * M;
    dst[lane] = make_float2(outre, outim);
}

// ---------------------------------------------------------------------------
// Per (b,h): S = tanh(Q^T K) (complex over e, double accum), then
// U[e][x] = sum_y S[x][y] K[e][y]
// ---------------------------------------------------------------------------
__global__ __launch_bounds__(256) void k_mid(const float2* __restrict__ Xq,
                                             const float2* __restrict__ Xk,
                                             float2* __restrict__ U)
{
    __shared__ float Qre[64][64], Qim[64][64];     // [e][m]
    __shared__ float KTre[64][65], KTim[64][65];   // [m][e] (padded)
    __shared__ float Sre[64][64], Sim[64][64];     // [y][x]

    int bh  = blockIdx.x;
    int tid = threadIdx.x;
    const float2* xq = Xq + (size_t)bh * 4096;
    const float2* xk = Xk + (size_t)bh * 4096;

    #pragma unroll
    for (int j = 0; j < 16; ++j) {
        int idx = tid + 256 * j;
        int e = idx >> 6, m = idx & 63;
        float2 vq = xq[idx];
        Qre[e][m] = vq.x; Qim[e][m] = vq.y;
        float2 vk = xk[idx];
        KTre[m][e] = vk.x; KTim[m][e] = vk.y;
    }
    __syncthreads();

    int x  = tid & 63;
    int y0 = (tid >> 6) * 16;
    double ar[16], ai[16];
    #pragma unroll
    for (int j = 0; j < 16; ++j) { ar[j] = 0.0; ai[j] = 0.0; }

    for (int e = 0; e < 64; ++e) {
        double qr = (double)Qre[e][x], qi = (double)Qim[e][x];
        #pragma unroll
        for (int j = 0; j < 16; ++j) {
            double kr = (double)KTre[y0 + j][e], ki = (double)KTim[y0 + j][e];
            ar[j] += qr * kr - qi * ki;
            ai[j] += qr * ki + qi * kr;
        }
    }
    #pragma unroll
    for (int j = 0; j < 16; ++j) {
        float tr, ti;
        ctanhf_stable((float)ar[j], (float)ai[j], tr, ti);
        Sre[y0 + j][x] = tr;
        Sim[y0 + j][x] = ti;
    }
    __syncthreads();

    int e0 = (tid >> 6) * 16;
    float ur[16], ui[16];
    #pragma unroll
    for (int j = 0; j < 16; ++j) { ur[j] = 0.f; ui[j] = 0.f; }

    for (int y = 0; y < 64; ++y) {
        float sr = Sre[y][x], si = Sim[y][x];
        #pragma unroll
        for (int j = 0; j < 16; ++j) {
            float kr = KTre[y][e0 + j], ki = KTim[y][e0 + j];
            ur[j] += sr * kr - si * ki;
            ui[j] += sr * ki + si * kr;
        }
    }
    #pragma unroll
    for (int j = 0; j < 16; ++j)
        U[((size_t)bh * 64 + (e0 + j)) * 64 + x] = make_float2(ur[j], ui[j]);
}

// ---------------------------------------------------------------------------
// Per (h, mode x): R[b][o] = sum_e U[b][e] * W[e][o]   (complex)
// ---------------------------------------------------------------------------
__global__ __launch_bounds__(256) void k_wmix(const float2* __restrict__ U,
                                              const float* __restrict__ w_re,
                                              const float* __restrict__ w_im,
                                              float2* __restrict__ R)
{
    __shared__ float2 Usm[16][64];                 // [b][e]
    __shared__ float Wre[64][64], Wim[64][64];     // [e][o]

    int h = blockIdx.x >> 6, x = blockIdx.x & 63;
    int tid = threadIdx.x;

    #pragma unroll
    for (int j = 0; j < 4; ++j) {
        int idx = tid + 256 * j;
        int b = idx >> 6, e = idx & 63;
        Usm[b][e] = U[((size_t)(b * H + h) * 64 + e) * 64 + x];
    }
    #pragma unroll
    for (int j = 0; j < 16; ++j) {
        int idx = tid + 256 * j;
        int e = idx >> 6, o = idx & 63;
        size_t off = ((size_t)(h * 64 + e) * 64 + o) * 64 + x;
        Wre[e][o] = w_re[off];
        Wim[e][o] = w_im[off];
    }
    __syncthreads();

    int o = tid & 63, b0 = tid >> 6;
    float rr[4], ri[4];
    #pragma unroll
    for (int j = 0; j < 4; ++j) { rr[j] = 0.f; ri[j] = 0.f; }

    for (int e = 0; e < 64; ++e) {
        float wr = Wre[e][o], wi = Wim[e][o];
        #pragma unroll
        for (int j = 0; j < 4; ++j) {
            float2 u = Usm[b0 + 4 * j][e];
            rr[j] += u.x * wr - u.y * wi;
            ri[j] += u.x * wi + u.y * wr;
        }
    }
    #pragma unroll
    for (int j = 0; j < 4; ++j) {
        int b = b0 + 4 * j;
        R[((size_t)(b * H + h) * 64 + o) * 64 + x] = make_float2(rr[j], ri[j]);
    }
}

// ---------------------------------------------------------------------------
// irFFT (modes 0..63 only):
// out[t] = sc*(0.5*Re F0 + sum_{m=1..63} Re(Fm e^{2pi i m t/L})), sc=2/(L*E*E)
// ---------------------------------------------------------------------------
__global__ __launch_bounds__(256) void k_irfft(const float2* __restrict__ R,
                                               float* __restrict__ out)
{
    __shared__ float2 F[64];
    int bho = blockIdx.x;                 // (b*H+h)*64 + o
    int o = bho & 63, bh = bho >> 6;
    int h = bh & 7, b = bh >> 3;
    int tid = threadIdx.x;

    if (tid < 64) F[tid] = R[(size_t)bho * 64 + tid];
    __syncthreads();

    float f0 = F[0].x;
    float wr[8], wi[8], cr[8], ci[8], acc[8];
    #pragma unroll
    for (int j = 0; j < 8; ++j) {
        int t = tid + 256 * j;
        float ang = 3.0679615757712823e-3f * (float)t;   // 2pi t / 2048
        float s, c;
        sincosf(ang, &s, &c);
        cr[j] = c; ci[j] = s;
        wr[j] = c; wi[j] = s;                            // m = 1
        acc[j] = 0.5f * f0;
    }
    #pragma unroll 1
    for (int m = 1; m < 64; ++m) {
        float2 f = F[m];
        #pragma unroll
        for (int j = 0; j < 8; ++j) {
            acc[j] += f.x * wr[j] - f.y * wi[j];
            float t = wr[j] * cr[j] - wi[j] * ci[j];     // w *= e^{2pi i t/L}
            wi[j] = wr[j] * ci[j] + wi[j] * cr[j];
            wr[j] = t;
        }
    }
    float* dst = out + ((size_t)(b * E + o) * H + h) * L;
    const float sc = 2.384185791015625e-7f;              // 2/(4096*2048)
    #pragma unroll
    for (int j = 0; j < 8; ++j) dst[tid + 256 * j] = acc[j] * sc;
}

// ---------------------------------------------------------------------------
extern "C" void kernel_launch(void* const* d_in, const int* in_sizes, int n_in,
                              void* d_out, int out_size, void* d_ws, size_t ws_size,
                              hipStream_t stream)
{
    (void)in_sizes; (void)n_in; (void)out_size; (void)ws_size;
    const float* q    = (const float*)d_in[0];
    const float* k    = (const float*)d_in[1];
    // d_in[2] = v, unused by the reference
    const float* w_re = (const float*)d_in[3];
    const float* w_im = (const float*)d_in[4];
    float* out = (float*)d_out;

    // Scratch plan: Xq, Xk, U live inside d_out (dead before k_irfft
    // overwrites the whole buffer). R survives into k_irfft -> d_ws.
    float2* Xq = (float2*)d_out;
    float2* Xk = Xq + PLANE;
    float2* Uu = Xk + PLANE;
    float2* R  = (float2*)d_ws;

    k_dft  <<<4096, 256, 0, stream>>>(q, k, Xq, Xk);
    k_mid  <<< 128, 256, 0, stream>>>(Xq, Xk, Uu);
    k_wmix <<< 512, 256, 0, stream>>>(Uu, w_re, w_im, R);
    k_irfft<<<8192, 256, 0, stream>>>(R, out);
}

// Round 3
// 129.135 us; speedup vs baseline: 3.2785x; 3.2785x over previous
//
#include <hip/hip_runtime.h>
#include <math.h>

#define B 16
#define E 64
#define H 8
#define L 2048
#define M 64
#define PLANE (B*H*E*M)   // 524288 float2 per spectral plane

// exact 32-pt DFT twiddles: CS32[j]=cos(pi j/16), SN32[j]=sin(pi j/16)
constexpr float CS32[32] = {
     1.0f,                    0.9807852804032304f,   0.9238795325112868f,   0.8314696123025452f,
     0.7071067811865476f,     0.5555702330196022f,   0.3826834323650898f,   0.1950903220161283f,
     0.0f,                   -0.1950903220161283f,  -0.3826834323650898f,  -0.5555702330196022f,
    -0.7071067811865476f,    -0.8314696123025452f,  -0.9238795325112868f,  -0.9807852804032304f,
    -1.0f,                   -0.9807852804032304f,  -0.9238795325112868f,  -0.8314696123025452f,
    -0.7071067811865476f,    -0.5555702330196022f,  -0.3826834323650898f,  -0.1950903220161283f,
     0.0f,                    0.1950903220161283f,   0.3826834323650898f,   0.5555702330196022f,
     0.7071067811865476f,     0.8314696123025452f,   0.9238795325112868f,   0.9807852804032304f
};
constexpr float SN32[32] = {
     0.0f,                    0.1950903220161283f,   0.3826834323650898f,   0.5555702330196022f,
     0.7071067811865476f,     0.8314696123025452f,   0.9238795325112868f,   0.9807852804032304f,
     1.0f,                    0.9807852804032304f,   0.9238795325112868f,   0.8314696123025452f,
     0.7071067811865476f,     0.5555702330196022f,   0.3826834323650898f,   0.1950903220161283f,
     0.0f,                   -0.1950903220161283f,  -0.3826834323650898f,  -0.5555702330196022f,
    -0.7071067811865476f,    -0.8314696123025452f,  -0.9238795325112868f,  -0.9807852804032304f,
    -1.0f,                   -0.9807852804032304f,  -0.9238795325112868f,  -0.8314696123025452f,
    -0.7071067811865476f,    -0.5555702330196022f,  -0.3826834323650898f,  -0.1950903220161283f
};

__device__ inline void ctanhf_stable(float x, float y, float& re, float& im) {
    float ax = fabsf(x);
    if (ax > 11.0f) { re = copysignf(1.0f, x); im = 0.0f; return; }
    float t    = tanf(y);
    float beta = 1.0f + t * t;
    float s    = sinhf(x);
    float rho  = sqrtf(1.0f + s * s);
    float den  = 1.0f + beta * s * s;
    re = (beta * rho * s) / den;
    im = t / den;
}

// ---------------------------------------------------------------------------
// Forward DFT, 4 rows per block, no cross-lane ops.
// Phase 1: thread (row, r=lane): Y_r[f] = sum_i x[64i+r] e^{-i pi f i/16},
//          f=0..16 (exact tables, i<->32-i fold). -> LDS.
// Phase 2: thread (row, m=lane): X[m] = sum_r e^{-i pi m r/1024} Y_r[m&31],
//          16-step-anchored twiddle recurrence, f64 accumulate.
// ---------------------------------------------------------------------------
__global__ __launch_bounds__(256) void k_dft(const float* __restrict__ q,
                                             const float* __restrict__ k,
                                             float2* __restrict__ Xq,
                                             float2* __restrict__ Xk)
{
    __shared__ float Yre[4][64][19], Yim[4][64][19];   // pad 19: conflict-free

    int rloc = threadIdx.x >> 6;
    int lane = threadIdx.x & 63;
    int rid  = blockIdx.x * 4 + rloc;                  // 0..16383
    int tensor = rid >> 13;
    int r8 = rid & 8191;
    int b = r8 >> 9, h = (r8 >> 6) & 7, e = r8 & 63;

    const float* src = (tensor ? k : q) + (((size_t)(b * E + e) * H + h) * L) + lane;
    float xs[32];
    #pragma unroll
    for (int i = 0; i < 32; ++i) xs[i] = src[i * 64];

    // fold: s_i = x_i + x_{32-i}, d_i = x_i - x_{32-i}
    float s_[16], d_[16];
    #pragma unroll
    for (int i = 1; i <= 15; ++i) { s_[i] = xs[i] + xs[32 - i]; d_[i] = xs[i] - xs[32 - i]; }

    float yre[17], yim[17];
    #pragma unroll
    for (int f = 0; f <= 16; ++f) {
        float ar = xs[0] + ((f & 1) ? -xs[16] : xs[16]);
        float ai = 0.f;
        #pragma unroll
        for (int i = 1; i <= 15; ++i) {
            ar = fmaf(s_[i], CS32[(f * i) & 31], ar);
            ai = fmaf(d_[i], SN32[(f * i) & 31], ai);
        }
        yre[f] = ar;
        yim[f] = -ai;
    }
    #pragma unroll
    for (int f = 0; f <= 16; ++f) { Yre[rloc][lane][f] = yre[f]; Yim[rloc][lane][f] = yim[f]; }
    __syncthreads();

    // phase 2
    int m  = lane;
    int f  = m & 31;
    int fi = (f <= 16) ? f : 32 - f;
    float sgn = (f <= 16) ? 1.f : -1.f;

    float us, uc;
    sincosf(-3.0679615757712823e-3f * (float)m, &us, &uc);   // step e^{-i pi m/1024}
    double ar = 0.0, ai = 0.0;

    #pragma unroll
    for (int seg = 0; seg < 4; ++seg) {
        float wi, wr;
        sincosf(-4.9087385212340519e-2f * (float)(m * seg), &wi, &wr); // anchor e^{-i pi m seg/64}
        #pragma unroll
        for (int rr = 0; rr < 16; ++rr) {
            int r = seg * 16 + rr;
            float yr = Yre[rloc][r][fi];
            float yi = sgn * Yim[rloc][r][fi];
            ar += (double)(yr * wr - yi * wi);
            ai += (double)(yr * wi + yi * wr);
            float t = fmaf(wr, uc, -wi * us);               // w *= step
            wi = fmaf(wr, us, wi * uc);
            wr = t;
        }
    }

    float2* dst = (tensor ? Xk : Xq) + ((size_t)(b * H + h) * E + e) * M;
    dst[m] = make_float2((float)ar, (float)ai);
}

// ---------------------------------------------------------------------------
// Per (bh, x-half): S = tanh(Q^T K) (f64 accum), U[e][x] = sum_y S[x][y]K[e][y]
// S aliases Q's LDS after a barrier (48 KB total).
// ---------------------------------------------------------------------------
__global__ __launch_bounds__(256) void k_mid(const float2* __restrict__ Xq,
                                             const float2* __restrict__ Xk,
                                             float2* __restrict__ U)
{
    __shared__ float Qre[64][32], Qim[64][32];   // [e][xl]; becomes S [y][xl]
    __shared__ float Kre[64][64], Kim[64][64];   // [e][m]

    int bh = blockIdx.x >> 1;
    int xh = (blockIdx.x & 1) * 32;
    int tid = threadIdx.x;
    const float2* xq = Xq + (size_t)bh * 4096;
    const float2* xk = Xk + (size_t)bh * 4096;

    #pragma unroll
    for (int j = 0; j < 8; ++j) {
        int idx = tid + 256 * j;                 // 2048 = 64e * 32x
        int e = idx >> 5, xl = idx & 31;
        float2 v = xq[(e << 6) + xh + xl];
        Qre[e][xl] = v.x; Qim[e][xl] = v.y;
    }
    #pragma unroll
    for (int j = 0; j < 16; ++j) {
        int idx = tid + 256 * j;                 // 4096 = 64e * 64m
        int e = idx >> 6, mm = idx & 63;
        float2 v = xk[idx];
        Kre[e][mm] = v.x; Kim[e][mm] = v.y;
    }
    __syncthreads();

    int x  = tid & 31;
    int y0 = (tid >> 5) * 8;
    double ar[8], ai[8];
    #pragma unroll
    for (int j = 0; j < 8; ++j) { ar[j] = 0.0; ai[j] = 0.0; }

    for (int e = 0; e < 64; ++e) {
        double qr = (double)Qre[e][x], qi = (double)Qim[e][x];
        #pragma unroll
        for (int j = 0; j < 8; ++j) {
            double kr = (double)Kre[e][y0 + j], ki = (double)Kim[e][y0 + j];
            ar[j] += qr * kr - qi * ki;
            ai[j] += qr * ki + qi * kr;
        }
    }
    float tr[8], ti[8];
    #pragma unroll
    for (int j = 0; j < 8; ++j) ctanhf_stable((float)ar[j], (float)ai[j], tr[j], ti[j]);

    __syncthreads();   // everyone done reading Q
    #pragma unroll
    for (int j = 0; j < 8; ++j) { Qre[y0 + j][x] = tr[j]; Qim[y0 + j][x] = ti[j]; }  // S[y][x]
    __syncthreads();

    int e0 = (tid >> 5) * 8;
    float ur[8], ui[8];
    #pragma unroll
    for (int j = 0; j < 8; ++j) { ur[j] = 0.f; ui[j] = 0.f; }

    for (int y = 0; y < 64; ++y) {
        float sr = Qre[y][x], si = Qim[y][x];
        #pragma unroll
        for (int j = 0; j < 8; ++j) {
            float kr = Kre[e0 + j][y], ki = Kim[e0 + j][y];
            ur[j] += sr * kr - si * ki;
            ui[j] += sr * ki + si * kr;
        }
    }
    #pragma unroll
    for (int j = 0; j < 8; ++j)
        U[((size_t)bh * 64 + (e0 + j)) * 64 + xh + x] = make_float2(ur[j], ui[j]);
}

// ---------------------------------------------------------------------------
// Per (h, mode x): R[b][o] = sum_e U[b][e] * W[e][o]   (complex)
// ---------------------------------------------------------------------------
__global__ __launch_bounds__(256) void k_wmix(const float2* __restrict__ U,
                                              const float* __restrict__ w_re,
                                              const float* __restrict__ w_im,
                                              float2* __restrict__ R)
{
    __shared__ float2 Usm[16][64];
    __shared__ float Wre[64][64], Wim[64][64];

    int h = blockIdx.x >> 6, x = blockIdx.x & 63;
    int tid = threadIdx.x;

    #pragma unroll
    for (int j = 0; j < 4; ++j) {
        int idx = tid + 256 * j;
        int b = idx >> 6, e = idx & 63;
        Usm[b][e] = U[((size_t)(b * H + h) * 64 + e) * 64 + x];
    }
    #pragma unroll
    for (int j = 0; j < 16; ++j) {
        int idx = tid + 256 * j;
        int e = idx >> 6, o = idx & 63;
        size_t off = ((size_t)(h * 64 + e) * 64 + o) * 64 + x;
        Wre[e][o] = w_re[off];
        Wim[e][o] = w_im[off];
    }
    __syncthreads();

    int o = tid & 63, b0 = tid >> 6;
    float rr[4], ri[4];
    #pragma unroll
    for (int j = 0; j < 4; ++j) { rr[j] = 0.f; ri[j] = 0.f; }

    for (int e = 0; e < 64; ++e) {
        float wr = Wre[e][o], wi = Wim[e][o];
        #pragma unroll
        for (int j = 0; j < 4; ++j) {
            float2 u = Usm[b0 + 4 * j][e];
            rr[j] += u.x * wr - u.y * wi;
            ri[j] += u.x * wi + u.y * wr;
        }
    }
    #pragma unroll
    for (int j = 0; j < 4; ++j) {
        int b = b0 + 4 * j;
        R[((size_t)(b * H + h) * 64 + o) * 64 + x] = make_float2(rr[j], ri[j]);
    }
}

// ---------------------------------------------------------------------------
// irFFT, 4 rows per block, no recurrence over outputs.
// Step A: thread (row, r=lane): G[f] = F[f] w^f + F[f+32] w^f c32,
//         w = e^{2pi i r/2048} (32-step recurrence), c32 = e^{2pi i r/64}.
//         G[0] -= 0.5 F0  (Re-only DC handling).
// Step B: out[64i+r] = Re sum_f W32^{fi} G[f]; parity fold i <-> i+16.
// ---------------------------------------------------------------------------
__global__ __launch_bounds__(256) void k_irfft(const float2* __restrict__ R,
                                               float* __restrict__ out)
{
    __shared__ float2 Fsh[4][64];
    int rloc = threadIdx.x >> 6;
    int r    = threadIdx.x & 63;
    int bho  = blockIdx.x * 4 + rloc;      // (b*H+h)*64 + o
    int o  = bho & 63, bh = bho >> 6;
    int h  = bh & 7,   b  = bh >> 3;

    Fsh[threadIdx.x >> 6][threadIdx.x & 63] = R[(size_t)blockIdx.x * 256 + threadIdx.x];
    __syncthreads();

    float sr_, cr_;
    sincosf(3.0679615757712823e-3f * (float)r, &sr_, &cr_);   // e^{2pi i r/2048}
    float s32, c32;
    sincosf(9.8174770424681038e-2f * (float)r, &s32, &c32);   // e^{2pi i r/64}

    float gr[32], gi[32];
    float wr = 1.f, wi = 0.f;
    #pragma unroll
    for (int f = 0; f < 32; ++f) {
        float2 Fa = Fsh[rloc][f];
        float2 Fb = Fsh[rloc][f + 32];
        float wbr = wr * c32 - wi * s32;
        float wbi = wr * s32 + wi * c32;
        gr[f] = wr * Fa.x - wi * Fa.y + wbr * Fb.x - wbi * Fb.y;
        gi[f] = wr * Fa.y + wi * Fa.x + wbr * Fb.y + wbi * Fb.x;
        float t = wr * cr_ - wi * sr_;
        wi = wr * sr_ + wi * cr_;
        wr = t;
    }
    gr[0] -= 0.5f * Fsh[rloc][0].x;

    const float scl = 2.384185791015625e-7f;   // 2/(4096*2048)
    float* dst = out + ((size_t)(b * E + o) * H + h) * L + r;
    #pragma unroll
    for (int i = 0; i < 16; ++i) {
        float ae = 0.f, ao = 0.f;
        #pragma unroll
        for (int f = 0; f < 32; f += 2) {
            ae = fmaf(gr[f],      CS32[(f * i) & 31],       ae);
            ae = fmaf(gi[f],     -SN32[(f * i) & 31],       ae);
            ao = fmaf(gr[f + 1],  CS32[((f + 1) * i) & 31], ao);
            ao = fmaf(gi[f + 1], -SN32[((f + 1) * i) & 31], ao);
        }
        dst[64 * i]        = scl * (ae + ao);
        dst[64 * (i + 16)] = scl * (ae - ao);
    }
}

// ---------------------------------------------------------------------------
extern "C" void kernel_launch(void* const* d_in, const int* in_sizes, int n_in,
                              void* d_out, int out_size, void* d_ws, size_t ws_size,
                              hipStream_t stream)
{
    (void)in_sizes; (void)n_in; (void)out_size; (void)ws_size;
    const float* q    = (const float*)d_in[0];
    const float* k    = (const float*)d_in[1];
    // d_in[2] = v, unused by the reference
    const float* w_re = (const float*)d_in[3];
    const float* w_im = (const float*)d_in[4];
    float* out = (float*)d_out;

    float2* Xq = (float2*)d_out;          // dead before k_irfft overwrites
    float2* Xk = Xq + PLANE;
    float2* Uu = Xk + PLANE;
    float2* R  = (float2*)d_ws;           // survives into k_irfft

    k_dft  <<<4096, 256, 0, stream>>>(q, k, Xq, Xk);
    k_mid  <<< 256, 256, 0, stream>>>(Xq, Xk, Uu);
    k_wmix <<< 512, 256, 0, stream>>>(Uu, w_re, w_im, R);
    k_irfft<<<2048, 256, 0, stream>>>(R, out);
}